// Round 4
// baseline (432.797 us; speedup 1.0000x reference)
//
#include <hip/hip_runtime.h>
#include <hip/hip_bf16.h>
#include <math.h>

// Shapes (fixed): B=32, O=1, L=2048, D=1024, D2=512. All I/O float32
// (verified round 2: bf16 interpretation NaN'd; f32 passed, absmax 2e-3).
#define NB 32
#define NL 2048
#define ND 1024
#define ND2 512
#define CH 32           // l-chunks per batch for k_flash
#define ROWS (NL / CH)  // 64 rows per block
#define RPW (ROWS / 4)  // 16 rows per wave

typedef float f4v __attribute__((ext_vector_type(4)));

__device__ __forceinline__ float waveReduceSumAll(float v) {
    for (int off = 32; off > 0; off >>= 1) v += __shfl_xor(v, off, 64);
    return v;
}
__device__ __forceinline__ float waveReduceSum(float v) {
    for (int off = 32; off > 0; off >>= 1) v += __shfl_down(v, off, 64);
    return v;
}

// q[b,e] = sum_d query[b,d] * W_in[e,d].
// W-stationary: 256 blocks x 4 e's; W_in row fragment lives in regs (read once
// chip-wide ~4 MB), query staged via LDS in two 64 KB halves (~32 MB L2 total).
__global__ __launch_bounds__(256) void k_qproj(const float* __restrict__ query,
                                               const float* __restrict__ W_in,
                                               float* __restrict__ q) {
    __shared__ float sq[16 * ND];   // 64 KB: 16 batch rows at a time
    int tid = threadIdx.x;
    int wave = tid >> 6, lane = tid & 63;
    int e = blockIdx.x * 4 + wave;
    const float4* wr = (const float4*)(W_in + (size_t)e * ND) + lane * 4;
    float4 w0 = wr[0], w1 = wr[1], w2 = wr[2], w3 = wr[3];

    for (int half = 0; half < 2; half++) {
        __syncthreads();   // protect sq from previous iteration's readers
        const float4* qsrc = (const float4*)(query + (size_t)half * 16 * ND);
        float4* qdst = (float4*)sq;
        for (int i = tid; i < 16 * ND / 4; i += 256) qdst[i] = qsrc[i];
        __syncthreads();
        for (int g = 0; g < 4; g++) {
            float p[4];
#pragma unroll
            for (int bb = 0; bb < 4; bb++) {
                const float4* qp = (const float4*)(sq + (g * 4 + bb) * ND) + lane * 4;
                float4 a0 = qp[0], a1 = qp[1], a2 = qp[2], a3 = qp[3];
                p[bb] = a0.x*w0.x + a0.y*w0.y + a0.z*w0.z + a0.w*w0.w
                      + a1.x*w1.x + a1.y*w1.y + a1.z*w1.z + a1.w*w1.w
                      + a2.x*w2.x + a2.y*w2.y + a2.z*w2.z + a2.w*w2.w
                      + a3.x*w3.x + a3.y*w3.y + a3.z*w3.z + a3.w*w3.w;
            }
#pragma unroll
            for (int off = 32; off > 0; off >>= 1) {
                p[0] += __shfl_down(p[0], off, 64);
                p[1] += __shfl_down(p[1], off, 64);
                p[2] += __shfl_down(p[2], off, 64);
                p[3] += __shfl_down(p[3], off, 64);
            }
            if (lane == 0) {
                int b0 = half * 16 + g * 4;
#pragma unroll
                for (int bb = 0; bb < 4; bb++) q[(b0 + bb) * ND + e] = p[bb];
            }
        }
    }
}

// Single pass over context: per (b, chunk) block, per-wave online softmax +
// weighted accumulation. Emits raw scores + per-block partials (m, Z, acc[ND]).
__global__ __launch_bounds__(256) void k_flash(const float* __restrict__ q,
                                               const float* __restrict__ ctx,
                                               const float* __restrict__ ae,
                                               const float* __restrict__ ab,
                                               float* __restrict__ scores,
                                               float* __restrict__ pm,
                                               float* __restrict__ pZ,
                                               float* __restrict__ pacc) {
    int b = blockIdx.x >> 5;       // CH == 32
    int chunk = blockIdx.x & 31;
    int wave = threadIdx.x >> 6;
    int lane = threadIdx.x & 63;

    const float4* qp = (const float4*)(q + (size_t)b * ND) + lane * 4;
    float4 q0 = qp[0], q1 = qp[1], q2 = qp[2], q3 = qp[3];
    float aev = ae[b], abv = ab[b];

    float m = -INFINITY, Z = 0.f;
    float acc[16];
#pragma unroll
    for (int j = 0; j < 16; j++) acc[j] = 0.f;

    int l0 = chunk * ROWS + wave * RPW;
    for (int i = 0; i < RPW; i++) {
        int l = l0 + i;
        const f4v* cp = (const f4v*)(ctx + ((size_t)b * NL + l) * ND) + lane * 4;
        f4v c0 = __builtin_nontemporal_load(cp + 0);
        f4v c1 = __builtin_nontemporal_load(cp + 1);
        f4v c2 = __builtin_nontemporal_load(cp + 2);
        f4v c3 = __builtin_nontemporal_load(cp + 3);
        float s = c0.x*q0.x + c0.y*q0.y + c0.z*q0.z + c0.w*q0.w
                + c1.x*q1.x + c1.y*q1.y + c1.z*q1.z + c1.w*q1.w
                + c2.x*q2.x + c2.y*q2.y + c2.z*q2.z + c2.w*q2.w
                + c3.x*q3.x + c3.y*q3.y + c3.z*q3.z + c3.w*q3.w;
        s = waveReduceSumAll(s);
        if (lane == 0) scores[b * NL + l] = s;

        float bt = __expf(-abv * (float)(NL - 1 - l));
        if (s > m) {                      // wave-uniform branch
            float sc = __expf(m - s);     // 0 on first row (m = -inf)
            m = s;
            Z *= sc;
#pragma unroll
            for (int j = 0; j < 16; j++) acc[j] *= sc;
        }
        float p = __expf(s - m);
        float k2 = p * aev * bt;
        Z += p;
        float c[16] = {c0.x,c0.y,c0.z,c0.w, c1.x,c1.y,c1.z,c1.w,
                       c2.x,c2.y,c2.z,c2.w, c3.x,c3.y,c3.z,c3.w};
#pragma unroll
        for (int j = 0; j < 16; j++)
            acc[j] += p * c[j] + k2 * fmaxf(c[j], 0.f);
    }

    __shared__ float sacc[4 * ND];   // 16 KB
    __shared__ float sm[4], sZ[4];
#pragma unroll
    for (int j = 0; j < 16; j++) sacc[wave * ND + lane * 16 + j] = acc[j];
    if (lane == 0) { sm[wave] = m; sZ[wave] = Z; }
    __syncthreads();

    int tid = threadIdx.x;
    float m0 = sm[0], m1 = sm[1], m2 = sm[2], m3 = sm[3];
    float mb = fmaxf(fmaxf(m0, m1), fmaxf(m2, m3));
    float e0 = __expf(m0 - mb), e1 = __expf(m1 - mb),
          e2 = __expf(m2 - mb), e3 = __expf(m3 - mb);
    int d = tid * 4;
    float4 v;
    v.x = e0*sacc[0*ND+d+0] + e1*sacc[1*ND+d+0] + e2*sacc[2*ND+d+0] + e3*sacc[3*ND+d+0];
    v.y = e0*sacc[0*ND+d+1] + e1*sacc[1*ND+d+1] + e2*sacc[2*ND+d+1] + e3*sacc[3*ND+d+1];
    v.z = e0*sacc[0*ND+d+2] + e1*sacc[1*ND+d+2] + e2*sacc[2*ND+d+2] + e3*sacc[3*ND+d+2];
    v.w = e0*sacc[0*ND+d+3] + e1*sacc[1*ND+d+3] + e2*sacc[2*ND+d+3] + e3*sacc[3*ND+d+3];
    *(float4*)(pacc + ((size_t)(b * CH + chunk)) * ND + d) = v;
    if (tid == 0) {
        pm[b * CH + chunk] = mb;
        pZ[b * CH + chunk] = e0*sZ[0] + e1*sZ[1] + e2*sZ[2] + e3*sZ[3];
    }
}

// Per-b merge of CH partials -> mixed[b,:], plus exact attn output.
__global__ __launch_bounds__(256) void k_merge(const float* __restrict__ pm,
                                               const float* __restrict__ pZ,
                                               const float* __restrict__ pacc,
                                               const float* __restrict__ scores,
                                               float* __restrict__ mixed,
                                               float* __restrict__ attn_out) {
    int b = blockIdx.x;
    int tid = threadIdx.x;
    __shared__ float ew[CH];
    __shared__ float smg, sinvZ;
    if (tid == 0) {
        float mg = -INFINITY;
        for (int i = 0; i < CH; i++) mg = fmaxf(mg, pm[b * CH + i]);
        float Zg = 0.f;
        for (int i = 0; i < CH; i++) Zg += __expf(pm[b * CH + i] - mg) * pZ[b * CH + i];
        smg = mg; sinvZ = 1.f / Zg;
    }
    __syncthreads();
    float mg = smg, invZ = sinvZ;
    if (tid < CH) ew[tid] = __expf(pm[b * CH + tid] - mg);
    __syncthreads();

    int d = tid * 4;
    float4 accv = {0.f, 0.f, 0.f, 0.f};
    for (int i = 0; i < CH; i++) {
        float4 pv = *(const float4*)(pacc + ((size_t)(b * CH + i)) * ND + d);
        float e = ew[i];
        accv.x += e * pv.x; accv.y += e * pv.y;
        accv.z += e * pv.z; accv.w += e * pv.w;
    }
    accv.x *= invZ; accv.y *= invZ; accv.z *= invZ; accv.w *= invZ;
    *(float4*)(mixed + (size_t)b * ND + d) = accv;

    for (int l = tid; l < NL; l += 256)
        attn_out[b * NL + l] = __expf(scores[b * NL + l] - mg) * invZ;
}

// out[b,e] = tanh( [mixed,q][b,:] . W_out[e,:] ); one wave per (b,e). 4096 blocks.
__global__ __launch_bounds__(256) void k_out(const float* __restrict__ mixed,
                                             const float* __restrict__ q,
                                             const float* __restrict__ W_out,
                                             float* __restrict__ out) {
    int wave = blockIdx.x * 4 + (threadIdx.x >> 6);
    int lane = threadIdx.x & 63;
    int b = wave >> 9;
    int e = wave & 511;
    int c0 = lane * 32;
    const float* src = (lane < 32) ? (mixed + (size_t)b * ND + c0)
                                   : (q + (size_t)b * ND + c0 - ND);
    const float4* wr = (const float4*)(W_out + (size_t)e * 2 * ND + c0);
    const float4* sp = (const float4*)src;
    float s = 0.f;
#pragma unroll
    for (int t = 0; t < 8; t++) {
        float4 w = wr[t], x = sp[t];
        s += w.x * x.x + w.y * x.y + w.z * x.z + w.w * x.w;
    }
    s = waveReduceSum(s);
    if (lane == 0) out[b * ND2 + e] = tanhf(s);
}

extern "C" void kernel_launch(void* const* d_in, const int* in_sizes, int n_in,
                              void* d_out, int out_size, void* d_ws, size_t ws_size,
                              hipStream_t stream) {
    const float* query = (const float*)d_in[0];
    const float* ctx   = (const float*)d_in[1];
    const float* W_in  = (const float*)d_in[2];
    const float* W_out = (const float*)d_in[3];
    const float* ae    = (const float*)d_in[4];
    const float* ab    = (const float*)d_in[5];
    float* out = (float*)d_out;                    // [NB, ND2]
    float* attn_out = out + (size_t)NB * ND2;      // [NB, NL]

    float* ws     = (float*)d_ws;
    float* q      = ws;                        // 32768
    float* scores = ws + 32768;                // 65536
    float* pm     = ws + 98304;                // 1024
    float* pZ     = ws + 99328;                // 1024
    float* pacc   = ws + 100352;               // NB*CH*ND = 1048576
    float* mixed  = ws + 1148928;              // 32768

    k_qproj<<<256, 256, 0, stream>>>(query, W_in, q);
    k_flash<<<NB * CH, 256, 0, stream>>>(q, ctx, ae, ab, scores, pm, pZ, pacc);
    k_merge<<<NB, 256, 0, stream>>>(pm, pZ, pacc, scores, mixed, attn_out);
    k_out<<<4096, 256, 0, stream>>>(mixed, q, W_out, out);
}

// Round 5
// 430.333 us; speedup vs baseline: 1.0057x; 1.0057x over previous
//
#include <hip/hip_runtime.h>
#include <hip/hip_bf16.h>
#include <math.h>

// Shapes (fixed): B=32, O=1, L=2048, D=1024, D2=512. All I/O float32
// (verified round 2: bf16 interpretation NaN'd; f32 passed, absmax 2e-3).
//
// Structure (round 5 = round 3's best-measured config):
//   k_qproj: GEMV q = query @ W_in^T, one wave per (b,e). L2-bound ~7 us.
//   k_flash: THE kernel — single fused pass over context (268 MB, HBM floor
//            ~43 us): scores + online softmax + weighted mix accumulation.
//            relu factors out of the sum since ae*attn*bt >= 0.
//   k_merge: per-b partial merge -> mixed, exact attn from stashed scores.
//   k_out:   GEMV + tanh epilogue.
#define NB 32
#define NL 2048
#define ND 1024
#define ND2 512
#define CH 32           // l-chunks per batch for k_flash
#define ROWS (NL / CH)  // 64 rows per block
#define RPW (ROWS / 4)  // 16 rows per wave

typedef float f4v __attribute__((ext_vector_type(4)));

__device__ __forceinline__ float waveReduceSumAll(float v) {
    for (int off = 32; off > 0; off >>= 1) v += __shfl_xor(v, off, 64);
    return v;
}
__device__ __forceinline__ float waveReduceSum(float v) {
    for (int off = 32; off > 0; off >>= 1) v += __shfl_down(v, off, 64);
    return v;
}

// q[b,e] = sum_d query[b,d] * W_in[e,d]; one wave per (b,e). 8192 blocks.
// (round-3 form: measured best; round-4 W-stationary variant regressed)
__global__ __launch_bounds__(256) void k_qproj(const float* __restrict__ query,
                                               const float* __restrict__ W_in,
                                               float* __restrict__ q) {
    int wave = blockIdx.x * 4 + (threadIdx.x >> 6);
    int lane = threadIdx.x & 63;
    int b = wave >> 10;
    int e = wave & 1023;
    const float4* qr = (const float4*)(query + (size_t)b * ND) + lane * 4;
    const float4* wr = (const float4*)(W_in + (size_t)e * ND) + lane * 4;
    float s = 0.f;
#pragma unroll
    for (int t = 0; t < 4; t++) {
        float4 a = qr[t], w = wr[t];
        s += a.x * w.x + a.y * w.y + a.z * w.z + a.w * w.w;
    }
    s = waveReduceSum(s);
    if (lane == 0) q[b * ND + e] = s;
}

// Single pass over context: per (b, chunk) block, per-wave online softmax +
// weighted accumulation. Emits raw scores + per-block partials (m, Z, acc[ND]).
__global__ __launch_bounds__(256) void k_flash(const float* __restrict__ q,
                                               const float* __restrict__ ctx,
                                               const float* __restrict__ ae,
                                               const float* __restrict__ ab,
                                               float* __restrict__ scores,
                                               float* __restrict__ pm,
                                               float* __restrict__ pZ,
                                               float* __restrict__ pacc) {
    int b = blockIdx.x >> 5;       // CH == 32
    int chunk = blockIdx.x & 31;
    int wave = threadIdx.x >> 6;
    int lane = threadIdx.x & 63;

    const float4* qp = (const float4*)(q + (size_t)b * ND) + lane * 4;
    float4 q0 = qp[0], q1 = qp[1], q2 = qp[2], q3 = qp[3];
    float aev = ae[b], abv = ab[b];

    float m = -INFINITY, Z = 0.f;
    float acc[16];
#pragma unroll
    for (int j = 0; j < 16; j++) acc[j] = 0.f;

    int l0 = chunk * ROWS + wave * RPW;
    for (int i = 0; i < RPW; i++) {
        int l = l0 + i;
        const f4v* cp = (const f4v*)(ctx + ((size_t)b * NL + l) * ND) + lane * 4;
        f4v c0 = __builtin_nontemporal_load(cp + 0);
        f4v c1 = __builtin_nontemporal_load(cp + 1);
        f4v c2 = __builtin_nontemporal_load(cp + 2);
        f4v c3 = __builtin_nontemporal_load(cp + 3);
        float s = c0.x*q0.x + c0.y*q0.y + c0.z*q0.z + c0.w*q0.w
                + c1.x*q1.x + c1.y*q1.y + c1.z*q1.z + c1.w*q1.w
                + c2.x*q2.x + c2.y*q2.y + c2.z*q2.z + c2.w*q2.w
                + c3.x*q3.x + c3.y*q3.y + c3.z*q3.z + c3.w*q3.w;
        s = waveReduceSumAll(s);
        if (lane == 0) scores[b * NL + l] = s;

        float bt = __expf(-abv * (float)(NL - 1 - l));
        if (s > m) {                      // wave-uniform branch
            float sc = __expf(m - s);     // 0 on first row (m = -inf)
            m = s;
            Z *= sc;
#pragma unroll
            for (int j = 0; j < 16; j++) acc[j] *= sc;
        }
        float p = __expf(s - m);
        float k2 = p * aev * bt;
        Z += p;
        float c[16] = {c0.x,c0.y,c0.z,c0.w, c1.x,c1.y,c1.z,c1.w,
                       c2.x,c2.y,c2.z,c2.w, c3.x,c3.y,c3.z,c3.w};
#pragma unroll
        for (int j = 0; j < 16; j++)
            acc[j] += p * c[j] + k2 * fmaxf(c[j], 0.f);
    }

    __shared__ float sacc[4 * ND];   // 16 KB
    __shared__ float sm[4], sZ[4];
#pragma unroll
    for (int j = 0; j < 16; j++) sacc[wave * ND + lane * 16 + j] = acc[j];
    if (lane == 0) { sm[wave] = m; sZ[wave] = Z; }
    __syncthreads();

    int tid = threadIdx.x;
    float m0 = sm[0], m1 = sm[1], m2 = sm[2], m3 = sm[3];
    float mb = fmaxf(fmaxf(m0, m1), fmaxf(m2, m3));
    float e0 = __expf(m0 - mb), e1 = __expf(m1 - mb),
          e2 = __expf(m2 - mb), e3 = __expf(m3 - mb);
    int d = tid * 4;
    float4 v;
    v.x = e0*sacc[0*ND+d+0] + e1*sacc[1*ND+d+0] + e2*sacc[2*ND+d+0] + e3*sacc[3*ND+d+0];
    v.y = e0*sacc[0*ND+d+1] + e1*sacc[1*ND+d+1] + e2*sacc[2*ND+d+1] + e3*sacc[3*ND+d+1];
    v.z = e0*sacc[0*ND+d+2] + e1*sacc[1*ND+d+2] + e2*sacc[2*ND+d+2] + e3*sacc[3*ND+d+2];
    v.w = e0*sacc[0*ND+d+3] + e1*sacc[1*ND+d+3] + e2*sacc[2*ND+d+3] + e3*sacc[3*ND+d+3];
    *(float4*)(pacc + ((size_t)(b * CH + chunk)) * ND + d) = v;
    if (tid == 0) {
        pm[b * CH + chunk] = mb;
        pZ[b * CH + chunk] = e0*sZ[0] + e1*sZ[1] + e2*sZ[2] + e3*sZ[3];
    }
}

// Per-b merge of CH partials -> mixed[b,:], plus exact attn output.
__global__ __launch_bounds__(256) void k_merge(const float* __restrict__ pm,
                                               const float* __restrict__ pZ,
                                               const float* __restrict__ pacc,
                                               const float* __restrict__ scores,
                                               float* __restrict__ mixed,
                                               float* __restrict__ attn_out) {
    int b = blockIdx.x;
    int tid = threadIdx.x;
    __shared__ float ew[CH];
    __shared__ float smg, sinvZ;
    if (tid == 0) {
        float mg = -INFINITY;
        for (int i = 0; i < CH; i++) mg = fmaxf(mg, pm[b * CH + i]);
        float Zg = 0.f;
        for (int i = 0; i < CH; i++) Zg += __expf(pm[b * CH + i] - mg) * pZ[b * CH + i];
        smg = mg; sinvZ = 1.f / Zg;
    }
    __syncthreads();
    float mg = smg, invZ = sinvZ;
    if (tid < CH) ew[tid] = __expf(pm[b * CH + tid] - mg);
    __syncthreads();

    int d = tid * 4;
    float4 accv = {0.f, 0.f, 0.f, 0.f};
    for (int i = 0; i < CH; i++) {
        float4 pv = *(const float4*)(pacc + ((size_t)(b * CH + i)) * ND + d);
        float e = ew[i];
        accv.x += e * pv.x; accv.y += e * pv.y;
        accv.z += e * pv.z; accv.w += e * pv.w;
    }
    accv.x *= invZ; accv.y *= invZ; accv.z *= invZ; accv.w *= invZ;
    *(float4*)(mixed + (size_t)b * ND + d) = accv;

    for (int l = tid; l < NL; l += 256)
        attn_out[b * NL + l] = __expf(scores[b * NL + l] - mg) * invZ;
}

// out[b,e] = tanh( [mixed,q][b,:] . W_out[e,:] ); one wave per (b,e). 4096 blocks.
__global__ __launch_bounds__(256) void k_out(const float* __restrict__ mixed,
                                             const float* __restrict__ q,
                                             const float* __restrict__ W_out,
                                             float* __restrict__ out) {
    int wave = blockIdx.x * 4 + (threadIdx.x >> 6);
    int lane = threadIdx.x & 63;
    int b = wave >> 9;
    int e = wave & 511;
    int c0 = lane * 32;
    const float* src = (lane < 32) ? (mixed + (size_t)b * ND + c0)
                                   : (q + (size_t)b * ND + c0 - ND);
    const float4* wr = (const float4*)(W_out + (size_t)e * 2 * ND + c0);
    const float4* sp = (const float4*)src;
    float s = 0.f;
#pragma unroll
    for (int t = 0; t < 8; t++) {
        float4 w = wr[t], x = sp[t];
        s += w.x * x.x + w.y * x.y + w.z * x.z + w.w * x.w;
    }
    s = waveReduceSum(s);
    if (lane == 0) out[b * ND2 + e] = tanhf(s);
}

extern "C" void kernel_launch(void* const* d_in, const int* in_sizes, int n_in,
                              void* d_out, int out_size, void* d_ws, size_t ws_size,
                              hipStream_t stream) {
    const float* query = (const float*)d_in[0];
    const float* ctx   = (const float*)d_in[1];
    const float* W_in  = (const float*)d_in[2];
    const float* W_out = (const float*)d_in[3];
    const float* ae    = (const float*)d_in[4];
    const float* ab    = (const float*)d_in[5];
    float* out = (float*)d_out;                    // [NB, ND2]
    float* attn_out = out + (size_t)NB * ND2;      // [NB, NL]

    float* ws     = (float*)d_ws;
    float* q      = ws;                        // 32768
    float* scores = ws + 32768;                // 65536
    float* pm     = ws + 98304;                // 1024
    float* pZ     = ws + 99328;                // 1024
    float* pacc   = ws + 100352;               // NB*CH*ND = 1048576
    float* mixed  = ws + 1148928;              // 32768

    k_qproj<<<8192, 256, 0, stream>>>(query, W_in, q);
    k_flash<<<NB * CH, 256, 0, stream>>>(q, ctx, ae, ab, scores, pm, pZ, pacc);
    k_merge<<<NB, 256, 0, stream>>>(pm, pZ, pacc, scores, mixed, attn_out);
    k_out<<<4096, 256, 0, stream>>>(mixed, q, W_out, out);
}